// Round 6
// baseline (855.936 us; speedup 1.0000x reference)
//
#include <hip/hip_runtime.h>
#include <hip/hip_bf16.h>
#include <stdint.h>

#define N_NODES 100000
#define N_EDGES 1600000
#define IN_DIM  384
#define HID_DIM 64
#define NPART   8
#define NP      (NPART * N_NODES)          // 800000 partitioned counters
#define SCAN8_NB 782                       // ceil(800000/1024)
#define EGRID   2048                       // hist/reorder grid (must match!)

typedef __attribute__((ext_vector_type(8))) short short8_t;
typedef __attribute__((ext_vector_type(4))) float f32x4;

// ---------------- runtime dtype detection ----------------
// flags[0]: edge_index is int64 (1) or int32 (0)
// flags[1]: mask mode: 0 = 16-bit (bf16/f16), 2 = f32, 3 = u8, 4 = i32
__global__ void k_detect(const uint32_t* __restrict__ ei,
                         const uint32_t* __restrict__ m1,
                         int* __restrict__ flags) {
    int l = threadIdx.x;  // 64 threads, 1 block
    uint32_t hi = ei[2 * l + 1];
    int ei64 = __all(hi == 0u);

    uint32_t maxb = 0;
    int bf = 0, f16 = 0, hib = 0;
    for (int i = 0; i < 4; ++i) {
        uint32_t w = m1[l * 4 + i];
        uint32_t b0 = w & 0xffu, b1 = (w >> 8) & 0xffu,
                 b2 = (w >> 16) & 0xffu, b3 = (w >> 24) & 0xffu;
        uint32_t mb = b0 > b1 ? b0 : b1;
        uint32_t mb2 = b2 > b3 ? b2 : b3;
        mb = mb > mb2 ? mb : mb2;
        maxb = maxb > mb ? maxb : mb;
        if ((w & 0xffffu) == 0x3f80u) bf = 1;
        if ((w & 0xffffu) == 0x3c00u) f16 = 1;
        if ((b1 | b2 | b3) != 0u) hib = 1;
    }
    int small  = __all(maxb <= 1u);
    int anybf  = __any(bf);
    int anyf16 = __any(f16);
    int anyhib = __any(hib);
    if (l == 0) {
        flags[0] = ei64;
        int mm;
        if (small)                 mm = anyhib ? 3 : 4;
        else if (anybf || anyf16)  mm = 0;
        else                       mm = 2;
        flags[1] = mm;
    }
}

__device__ __forceinline__ float mask_at(const void* p, int mode, long idx) {
    if (mode == 0) return ((const uint16_t*)p)[idx] ? 2.0f : 0.0f;
    if (mode == 2) return ((const float*)p)[idx] != 0.0f ? 2.0f : 0.0f;
    if (mode == 3) return ((const uint8_t*)p)[idx] ? 2.0f : 0.0f;
    return ((const int*)p)[idx] ? 2.0f : 0.0f;
}

__device__ __forceinline__ void load_edge(const int* p32, int mode64, long e,
                                          int& s, int& d) {
    if (mode64) { s = p32[2 * e]; d = p32[2 * (N_EDGES + e)]; }
    else        { s = p32[e];     d = p32[N_EDGES + e]; }
}

// f32 -> bf16 RNE, and back
__device__ __forceinline__ ushort f2bf(float f) {
    uint32_t u = __float_as_uint(f);
    return (ushort)((u + 0x7fffu + ((u >> 16) & 1u)) >> 16);
}
__device__ __forceinline__ float bf2f(ushort h) {
    return __uint_as_float(((uint32_t)h) << 16);
}

// ---------------- CSR build: partitioned histogram ----------------
// partition p = blockIdx & 7 (heuristic XCD id; correctness-independent).
// MUST use the same grid geometry as k_reorder8 so each edge maps to the
// same partition in both kernels.
__global__ __launch_bounds__(256) void k_hist8(const void* __restrict__ ei,
                                               uint32_t* __restrict__ deg8,
                                               const int* __restrict__ flags) {
    const int mode64 = flags[0];
    const int* p32 = (const int*)ei;
    const long pbase = (long)(blockIdx.x & (NPART - 1)) * N_NODES;
    for (long e = (long)blockIdx.x * 256 + threadIdx.x; e < N_EDGES;
         e += (long)EGRID * 256) {
        int s, d; load_edge(p32, mode64, e, s, d);
        atomicAdd(&deg8[pbase + d], 1u);
    }
}

// ---------------- CSR build: 800K-entry scan (3 kernels) ----------------
__global__ __launch_bounds__(256) void k_scanA8(const uint32_t* __restrict__ deg,
                                                uint32_t* __restrict__ partials) {
    __shared__ uint32_t sbuf[256];
    long base = (long)blockIdx.x * 1024 + threadIdx.x * 4;
    uint32_t s = 0;
    if (base + 3 < NP) {
        uint4 v = *(const uint4*)&deg[base];
        s = v.x + v.y + v.z + v.w;
    } else {
        for (int j = 0; j < 4; ++j) if (base + j < NP) s += deg[base + j];
    }
    sbuf[threadIdx.x] = s;
    __syncthreads();
    for (int off = 128; off > 0; off >>= 1) {
        if (threadIdx.x < off) sbuf[threadIdx.x] += sbuf[threadIdx.x + off];
        __syncthreads();
    }
    if (threadIdx.x == 0) partials[blockIdx.x] = sbuf[0];
}

__global__ __launch_bounds__(1024) void k_scanB8(const uint32_t* __restrict__ partials,
                                                 uint32_t* __restrict__ poff,
                                                 uint32_t* __restrict__ starts) {
    __shared__ uint32_t sbuf[1024];
    int t = threadIdx.x;
    uint32_t v = t < SCAN8_NB ? partials[t] : 0u;
    sbuf[t] = v;
    __syncthreads();
    for (int off = 1; off < 1024; off <<= 1) {
        uint32_t add = t >= off ? sbuf[t - off] : 0u;
        __syncthreads();
        sbuf[t] += add;
        __syncthreads();
    }
    if (t < SCAN8_NB) poff[t] = sbuf[t] - v;            // exclusive
    if (t == SCAN8_NB - 1) starts[NP] = sbuf[t];        // sentinel = E
}

// writes starts AND cursor copy (saves a D2D memcpy)
__global__ __launch_bounds__(256) void k_scanC8(const uint32_t* __restrict__ deg,
                                                const uint32_t* __restrict__ poff,
                                                uint32_t* __restrict__ starts,
                                                uint32_t* __restrict__ cur) {
    __shared__ uint32_t sbuf[256];
    long base = (long)blockIdx.x * 1024 + threadIdx.x * 4;
    uint32_t v[4] = {0, 0, 0, 0};
    if (base + 3 < NP) {
        uint4 q = *(const uint4*)&deg[base];
        v[0] = q.x; v[1] = q.y; v[2] = q.z; v[3] = q.w;
    } else {
        for (int j = 0; j < 4; ++j) if (base + j < NP) v[j] = deg[base + j];
    }
    uint32_t ts = v[0] + v[1] + v[2] + v[3];
    sbuf[threadIdx.x] = ts;
    __syncthreads();
    for (int off = 1; off < 256; off <<= 1) {
        uint32_t add = threadIdx.x >= off ? sbuf[threadIdx.x - off] : 0u;
        __syncthreads();
        sbuf[threadIdx.x] += add;
        __syncthreads();
    }
    uint32_t run = poff[blockIdx.x] + sbuf[threadIdx.x] - ts;
    for (int j = 0; j < 4; ++j) {
        if (base + j < NP) {
            starts[base + j] = run;
            cur[base + j]    = run;
            run += v[j];
        }
    }
}

// ---------------- CSR build: partitioned reorder ----------------
// Partition p's output region is contiguous (~1.6MB) and written only by
// blocks with blockIdx&7 == p (≈ one XCD) -> lines accumulate in that L2
// before a single flush instead of per-entry flushes.
__global__ __launch_bounds__(256) void k_reorder8(const void* __restrict__ ei,
                                                  const float* __restrict__ ew,
                                                  uint32_t* __restrict__ cur8,
                                                  int2* __restrict__ sorted,
                                                  const int* __restrict__ flags) {
    const int mode64 = flags[0];
    const int* p32 = (const int*)ei;
    const long pbase = (long)(blockIdx.x & (NPART - 1)) * N_NODES;
    for (long e = (long)blockIdx.x * 256 + threadIdx.x; e < N_EDGES;
         e += (long)EGRID * 256) {
        int s, d; load_edge(p32, mode64, e, s, d);
        float w = ew[e];
        uint32_t pos = atomicAdd(&cur8[pbase + d], 1u);
        sorted[pos] = make_int2(s, __float_as_int(w));
    }
}

// ---------------- pre-pack W1 into bf16 hi/lo B-fragments ----------------
__global__ __launch_bounds__(256) void k_packW(const float* __restrict__ W1,
                                               ushort* __restrict__ Wpack) {
    const int ks = blockIdx.x;        // 0..11
    const int t  = threadIdx.x;
    const int nt = t >> 6, l = t & 63;
    ushort hs[8], ls[8];
#pragma unroll
    for (int j = 0; j < 8; ++j) {
        float wv = W1[(ks * 32 + (l >> 4) * 8 + j) * 64 + nt * 16 + (l & 15)];
        ushort h = f2bf(wv);
        hs[j] = h;
        ls[j] = f2bf(wv - bf2f(h));
    }
    *(short8_t*)&Wpack[((8 * ks + nt) * 64 + l) * 8]     = *(short8_t*)hs;
    *(short8_t*)&Wpack[((8 * ks + 4 + nt) * 64 + l) * 8] = *(short8_t*)ls;
}

// ---------------- GEMM1: H = bf16((x .* m1 * 2) @ W1), no LDS ----------------
__global__ __launch_bounds__(256) void k1_mfma(
        const float* __restrict__ x, const void* __restrict__ m1,
        const ushort* __restrict__ Wpack, ushort* __restrict__ Hb,
        const int* __restrict__ flags) {
    const int mmode = flags[1];
    const int t = threadIdx.x;
    const int l = t & 63, w = t >> 6;
    const int node0 = blockIdx.x * 64;
    const long row = node0 + w * 16 + (l & 15);
    const int kq = (l >> 4) * 8;
    const bool valid = row < N_NODES;

    f32x4 acc[4];
#pragma unroll
    for (int i = 0; i < 4; ++i) acc[i] = (f32x4)0.0f;

    for (int ks = 0; ks < 12; ++ks) {
        float xv[8];
        if (valid) {
            long gb = row * IN_DIM + ks * 32 + kq;
            float4 x0 = *(const float4*)(x + gb);
            float4 x1 = *(const float4*)(x + gb + 4);
            xv[0] = x0.x; xv[1] = x0.y; xv[2] = x0.z; xv[3] = x0.w;
            xv[4] = x1.x; xv[5] = x1.y; xv[6] = x1.z; xv[7] = x1.w;
            float mv[8];
            if (mmode == 0) {
                const ushort* mp = (const ushort*)m1 + gb;
                ushort4 a = *(const ushort4*)mp;
                ushort4 b = *(const ushort4*)(mp + 4);
                mv[0] = a.x ? 2.f : 0.f; mv[1] = a.y ? 2.f : 0.f;
                mv[2] = a.z ? 2.f : 0.f; mv[3] = a.w ? 2.f : 0.f;
                mv[4] = b.x ? 2.f : 0.f; mv[5] = b.y ? 2.f : 0.f;
                mv[6] = b.z ? 2.f : 0.f; mv[7] = b.w ? 2.f : 0.f;
            } else if (mmode == 2) {
                const float* mp = (const float*)m1 + gb;
                float4 a = *(const float4*)mp;
                float4 b = *(const float4*)(mp + 4);
                mv[0] = a.x != 0.f ? 2.f : 0.f; mv[1] = a.y != 0.f ? 2.f : 0.f;
                mv[2] = a.z != 0.f ? 2.f : 0.f; mv[3] = a.w != 0.f ? 2.f : 0.f;
                mv[4] = b.x != 0.f ? 2.f : 0.f; mv[5] = b.y != 0.f ? 2.f : 0.f;
                mv[6] = b.z != 0.f ? 2.f : 0.f; mv[7] = b.w != 0.f ? 2.f : 0.f;
            } else if (mmode == 3) {
                uint2 mb = *(const uint2*)((const uint8_t*)m1 + gb);
#pragma unroll
                for (int j = 0; j < 4; ++j) {
                    mv[j]     = ((mb.x >> (8 * j)) & 0xffu) ? 2.f : 0.f;
                    mv[4 + j] = ((mb.y >> (8 * j)) & 0xffu) ? 2.f : 0.f;
                }
            } else {
                const int* mp = (const int*)m1 + gb;
                int4 a = *(const int4*)mp;
                int4 b = *(const int4*)(mp + 4);
                mv[0] = a.x ? 2.f : 0.f; mv[1] = a.y ? 2.f : 0.f;
                mv[2] = a.z ? 2.f : 0.f; mv[3] = a.w ? 2.f : 0.f;
                mv[4] = b.x ? 2.f : 0.f; mv[5] = b.y ? 2.f : 0.f;
                mv[6] = b.z ? 2.f : 0.f; mv[7] = b.w ? 2.f : 0.f;
            }
#pragma unroll
            for (int j = 0; j < 8; ++j) xv[j] *= mv[j];
        } else {
#pragma unroll
            for (int j = 0; j < 8; ++j) xv[j] = 0.0f;
        }
        ushort ap[8];
#pragma unroll
        for (int j = 0; j < 8; ++j) ap[j] = f2bf(xv[j]);
        short8_t ah = *(short8_t*)ap;

#pragma unroll
        for (int nt = 0; nt < 4; ++nt) {
            short8_t bh = *(const short8_t*)&Wpack[((8 * ks + nt) * 64 + l) * 8];
            short8_t bl = *(const short8_t*)&Wpack[((8 * ks + 4 + nt) * 64 + l) * 8];
            acc[nt] = __builtin_amdgcn_mfma_f32_16x16x32_bf16(ah, bh, acc[nt], 0, 0, 0);
            acc[nt] = __builtin_amdgcn_mfma_f32_16x16x32_bf16(ah, bl, acc[nt], 0, 0, 0);
        }
    }
    const int r0 = (l >> 4) * 4;
#pragma unroll
    for (int nt = 0; nt < 4; ++nt) {
#pragma unroll
        for (int r = 0; r < 4; ++r) {
            long node = node0 + w * 16 + r0 + r;
            if (node < N_NODES)
                Hb[node * 64 + nt * 16 + (l & 15)] = f2bf(acc[nt][r]);
        }
    }
}

// gather-accumulate one node's 8 partition segments
__device__ __forceinline__ float agg_node(const ushort* __restrict__ Hb,
                                          const int2* __restrict__ sorted,
                                          const uint32_t* __restrict__ starts,
                                          int n, int lane) {
    float acc = 0.0f;
#pragma unroll 1
    for (int p = 0; p < NPART; ++p) {
        uint32_t e  = starts[p * N_NODES + n];
        uint32_t e1 = starts[p * N_NODES + n + 1];
        for (; e + 2 <= e1; e += 2) {
            int2 p0 = sorted[e];
            int2 p1 = sorted[e + 1];
            float v0 = bf2f(Hb[(long)p0.x * 64 + lane]);
            float v1 = bf2f(Hb[(long)p1.x * 64 + lane]);
            acc = fmaf(v0, __int_as_float(p0.y), acc);
            acc = fmaf(v1, __int_as_float(p1.y), acc);
        }
        if (e < e1) {
            int2 p0 = sorted[e];
            acc = fmaf(bf2f(Hb[(long)p0.x * 64 + lane]), __int_as_float(p0.y), acc);
        }
    }
    return acc;
}

// ---------------- fused: agg1(bf16 gather) + b1 + relu + mask2 + @W2 -> bf16 ----
// grid must be exactly N_NODES/4 blocks.
__global__ __launch_bounds__(256) void k_aggmlp(
        const ushort* __restrict__ Hb, const int2* __restrict__ sorted,
        const uint32_t* __restrict__ starts, const float* __restrict__ b1,
        const void* __restrict__ m2, const float* __restrict__ W2,
        ushort* __restrict__ H2b, const int* __restrict__ flags) {
    __shared__ float w2s[64 * 64];
    __shared__ float vbuf[4][64];
    const int mmode = flags[1];
    for (int i = threadIdx.x; i < 4096; i += 256) w2s[i] = W2[i];
    __syncthreads();

    const int lane = threadIdx.x & 63;
    const int w = threadIdx.x >> 6;
    const int n = blockIdx.x * 4 + w;
    float acc = agg_node(Hb, sorted, starts, n, lane);
    float u = acc + b1[lane];
    u = u > 0.0f ? u : 0.0f;
    u *= mask_at(m2, mmode, (long)n * 64 + lane);
    vbuf[w][lane] = u;  // wave-local LDS: in-order, no barrier needed
    float h2 = 0.0f;
#pragma unroll
    for (int j = 0; j < 64; j += 4) {
        float4 v4 = *(const float4*)&vbuf[w][j];
        h2 = fmaf(v4.x, w2s[(j + 0) * 64 + lane], h2);
        h2 = fmaf(v4.y, w2s[(j + 1) * 64 + lane], h2);
        h2 = fmaf(v4.z, w2s[(j + 2) * 64 + lane], h2);
        h2 = fmaf(v4.w, w2s[(j + 3) * 64 + lane], h2);
    }
    H2b[(long)n * 64 + lane] = f2bf(h2);
}

// ---------------- final: out = b2 + agg2(bf16 gather), f32 out ----------------
__global__ __launch_bounds__(256) void k_agg(const ushort* __restrict__ Hb,
                                             const int2* __restrict__ sorted,
                                             const uint32_t* __restrict__ starts,
                                             const float* __restrict__ bias,
                                             float* __restrict__ dest) {
    const int lane = threadIdx.x & 63;
    const int n = blockIdx.x * 4 + (threadIdx.x >> 6);
    if (n >= N_NODES) return;
    float acc = bias[lane] + agg_node(Hb, sorted, starts, n, lane);
    dest[(long)n * 64 + lane] = acc;
}

// ---------------- fallback atomic path ----------------
__global__ __launch_bounds__(256) void k_scatter(
        const ushort* __restrict__ Hb, const void* __restrict__ ei,
        const float* __restrict__ ew, float* __restrict__ dest,
        const int* __restrict__ flags) {
    const int mode64 = flags[0];
    const int lane = threadIdx.x & 63;
    const long wid = (long)blockIdx.x * 4 + (threadIdx.x >> 6);
    const long nw = (long)gridDim.x * 4;
    const int* p32 = (const int*)ei;
    for (long e = wid; e < N_EDGES; e += nw) {
        int s, d; load_edge(p32, mode64, e, s, d);
        float w = ew[e];
        float v = bf2f(Hb[(long)s * 64 + lane]) * w;
        atomicAdd(&dest[(long)d * 64 + lane], v);
    }
}

__global__ __launch_bounds__(256) void k3_mlp(
        const float* __restrict__ agg, const float* __restrict__ b1,
        const void* __restrict__ m2, const float* __restrict__ W2,
        ushort* __restrict__ H2b, const int* __restrict__ flags) {
    __shared__ float w2s[64 * 64];
    __shared__ float vbuf[4][64];
    const int mmode = flags[1];
    for (int i = threadIdx.x; i < 4096; i += 256) w2s[i] = W2[i];
    __syncthreads();
    const int lane = threadIdx.x & 63;
    const int w = threadIdx.x >> 6;
    const float bc = b1[lane];
    const long wid = (long)blockIdx.x * 4 + w;
    const long nw = (long)gridDim.x * 4;
    for (long n = wid; n < N_NODES; n += nw) {
        float u = agg[n * 64 + lane] + bc;
        u = u > 0.0f ? u : 0.0f;
        u *= mask_at(m2, mmode, n * 64 + lane);
        vbuf[w][lane] = u;
        float acc = 0.0f;
#pragma unroll
        for (int j = 0; j < 64; j += 4) {
            float4 v4 = *(const float4*)&vbuf[w][j];
            acc = fmaf(v4.x, w2s[(j + 0) * 64 + lane], acc);
            acc = fmaf(v4.y, w2s[(j + 1) * 64 + lane], acc);
            acc = fmaf(v4.z, w2s[(j + 2) * 64 + lane], acc);
            acc = fmaf(v4.w, w2s[(j + 3) * 64 + lane], acc);
        }
        H2b[n * 64 + lane] = f2bf(acc);
    }
}

__global__ void k_init_out(float* __restrict__ out, const float* __restrict__ b2) {
    const long total = (long)N_NODES * 16;
    for (long j = (long)blockIdx.x * 256 + threadIdx.x; j < total;
         j += (long)gridDim.x * 256) {
        ((float4*)out)[j] = ((const float4*)b2)[j & 15];
    }
}

extern "C" void kernel_launch(void* const* d_in, const int* in_sizes, int n_in,
                              void* d_out, int out_size, void* d_ws, size_t ws_size,
                              hipStream_t stream) {
    const float* x  = (const float*)d_in[0];
    const void*  ei = d_in[1];
    const float* ew = (const float*)d_in[2];
    const float* W1 = (const float*)d_in[3];
    const float* b1 = (const float*)d_in[4];
    const float* W2 = (const float*)d_in[5];
    const float* b2 = (const float*)d_in[6];
    const void*  m1 = d_in[7];
    const void*  m2 = d_in[8];
    float* out = (float*)d_out;

    char* ws = (char*)d_ws;
    size_t off = 0;
    auto alloc = [&](size_t bytes) {
        char* p = ws + off;
        off += (bytes + 255) & ~(size_t)255;
        return p;
    };
    int*    flags = (int*)alloc(32);
    ushort* Hb    = (ushort*)alloc((size_t)N_NODES * 64 * 2);
    ushort* H2b   = (ushort*)alloc((size_t)N_NODES * 64 * 2);
    // overlay region: CSR arrays (22.4MB) alias fallback AGG (25.6MB)
    char*   region = alloc((size_t)N_NODES * 64 * 4);
    int2*     sorted = (int2*)region;                                  // 12.8MB
    uint32_t* starts = (uint32_t*)(region + (size_t)N_EDGES * 8);      // 3.2MB+4
    uint32_t* cur8   = starts + (NP + 64);                             // 3.2MB
    uint32_t* deg8   = cur8 + NP;                                      // 3.2MB
    float*    AGG    = (float*)region;                                 // fallback
    uint32_t* partials = (uint32_t*)alloc((size_t)SCAN8_NB * 4);
    uint32_t* poff     = (uint32_t*)alloc((size_t)SCAN8_NB * 4);
    ushort*   Wpack    = (ushort*)alloc((size_t)12 * 8 * 64 * 8 * 2);
    size_t need = off;

    hipLaunchKernelGGL(k_detect, dim3(1), dim3(64), 0, stream,
                       (const uint32_t*)ei, (const uint32_t*)m1, flags);
    hipLaunchKernelGGL(k_packW, dim3(12), dim3(256), 0, stream, W1, Wpack);

    if (ws_size >= need) {
        // --- partitioned-CSR path ---
        hipMemsetAsync(deg8, 0, (size_t)NP * 4, stream);
        hipLaunchKernelGGL(k_hist8, dim3(EGRID), dim3(256), 0, stream,
                           ei, deg8, flags);
        hipLaunchKernelGGL(k_scanA8, dim3(SCAN8_NB), dim3(256), 0, stream,
                           deg8, partials);
        hipLaunchKernelGGL(k_scanB8, dim3(1), dim3(1024), 0, stream,
                           partials, poff, starts);
        hipLaunchKernelGGL(k_scanC8, dim3(SCAN8_NB), dim3(256), 0, stream,
                           deg8, poff, starts, cur8);
        hipLaunchKernelGGL(k_reorder8, dim3(EGRID), dim3(256), 0, stream,
                           ei, ew, cur8, sorted, flags);
        hipLaunchKernelGGL(k1_mfma, dim3((N_NODES + 63) / 64), dim3(256), 0, stream,
                           x, m1, Wpack, Hb, flags);
        hipLaunchKernelGGL(k_aggmlp, dim3(N_NODES / 4), dim3(256), 0, stream,
                           Hb, sorted, starts, b1, m2, W2, H2b, flags);
        hipLaunchKernelGGL(k_agg, dim3(N_NODES / 4), dim3(256), 0, stream,
                           H2b, sorted, starts, b2, out);
    } else {
        // --- fallback: atomic path ---
        hipMemsetAsync(AGG, 0, (size_t)N_NODES * 64 * 4, stream);
        hipLaunchKernelGGL(k1_mfma, dim3((N_NODES + 63) / 64), dim3(256), 0, stream,
                           x, m1, Wpack, Hb, flags);
        hipLaunchKernelGGL(k_scatter, dim3(4096), dim3(256), 0, stream,
                           Hb, ei, ew, AGG, flags);
        hipLaunchKernelGGL(k3_mlp, dim3(1024), dim3(256), 0, stream,
                           AGG, b1, m2, W2, H2b, flags);
        hipLaunchKernelGGL(k_init_out, dim3(2048), dim3(256), 0, stream, out, b2);
        hipLaunchKernelGGL(k_scatter, dim3(4096), dim3(256), 0, stream,
                           H2b, ei, ew, out, flags);
    }
}

// Round 8
// 718.895 us; speedup vs baseline: 1.1906x; 1.1906x over previous
//
#include <hip/hip_runtime.h>
#include <hip/hip_bf16.h>
#include <stdint.h>

#define N_NODES 100000
#define N_EDGES 1600000
#define IN_DIM  384
#define HID_DIM 64
#define NPART   8
#define NP      (NPART * N_NODES)          // 800000 partitioned counters
#define SCAN8_NB 782                       // ceil(800000/1024)
#define SCANF_NB 391                       // ceil(100000/256)
#define EGRID   2048                       // hist/reorder grid (must match!)

typedef __attribute__((ext_vector_type(8))) short short8_t;
typedef __attribute__((ext_vector_type(4))) float f32x4;

// ---------------- runtime dtype detection ----------------
// flags[0]: edge_index is int64 (1) or int32 (0)
// flags[1]: mask mode: 0 = 16-bit (bf16/f16), 2 = f32, 3 = u8, 4 = i32
__global__ void k_detect(const uint32_t* __restrict__ ei,
                         const uint32_t* __restrict__ m1,
                         int* __restrict__ flags) {
    int l = threadIdx.x;  // 64 threads, 1 block
    uint32_t hi = ei[2 * l + 1];
    int ei64 = __all(hi == 0u);

    uint32_t maxb = 0;
    int bf = 0, f16 = 0, hib = 0;
    for (int i = 0; i < 4; ++i) {
        uint32_t w = m1[l * 4 + i];
        uint32_t b0 = w & 0xffu, b1 = (w >> 8) & 0xffu,
                 b2 = (w >> 16) & 0xffu, b3 = (w >> 24) & 0xffu;
        uint32_t mb = b0 > b1 ? b0 : b1;
        uint32_t mb2 = b2 > b3 ? b2 : b3;
        mb = mb > mb2 ? mb : mb2;
        maxb = maxb > mb ? maxb : mb;
        if ((w & 0xffffu) == 0x3f80u) bf = 1;
        if ((w & 0xffffu) == 0x3c00u) f16 = 1;
        if ((b1 | b2 | b3) != 0u) hib = 1;
    }
    int small  = __all(maxb <= 1u);
    int anybf  = __any(bf);
    int anyf16 = __any(f16);
    int anyhib = __any(hib);
    if (l == 0) {
        flags[0] = ei64;
        int mm;
        if (small)                 mm = anyhib ? 3 : 4;
        else if (anybf || anyf16)  mm = 0;
        else                       mm = 2;
        flags[1] = mm;
    }
}

__device__ __forceinline__ float mask_at(const void* p, int mode, long idx) {
    if (mode == 0) return ((const uint16_t*)p)[idx] ? 2.0f : 0.0f;
    if (mode == 2) return ((const float*)p)[idx] != 0.0f ? 2.0f : 0.0f;
    if (mode == 3) return ((const uint8_t*)p)[idx] ? 2.0f : 0.0f;
    return ((const int*)p)[idx] ? 2.0f : 0.0f;
}

__device__ __forceinline__ void load_edge(const int* p32, int mode64, long e,
                                          int& s, int& d) {
    if (mode64) { s = p32[2 * e]; d = p32[2 * (N_EDGES + e)]; }
    else        { s = p32[e];     d = p32[N_EDGES + e]; }
}

// f32 -> bf16 RNE, and back
__device__ __forceinline__ ushort f2bf(float f) {
    uint32_t u = __float_as_uint(f);
    return (ushort)((u + 0x7fffu + ((u >> 16) & 1u)) >> 16);
}
__device__ __forceinline__ float bf2f(ushort h) {
    return __uint_as_float(((uint32_t)h) << 16);
}

// ---------------- CSR build: partitioned histogram ----------------
__global__ __launch_bounds__(256) void k_hist8(const void* __restrict__ ei,
                                               uint32_t* __restrict__ deg8,
                                               const int* __restrict__ flags) {
    const int mode64 = flags[0];
    const int* p32 = (const int*)ei;
    const long pbase = (long)(blockIdx.x & (NPART - 1)) * N_NODES;
    for (long e = (long)blockIdx.x * 256 + threadIdx.x; e < N_EDGES;
         e += (long)EGRID * 256) {
        int s, d; load_edge(p32, mode64, e, s, d);
        atomicAdd(&deg8[pbase + d], 1u);
    }
}

// ---------------- 800K-entry scan (3 kernels) -> starts8 + cur8 ----------------
__global__ __launch_bounds__(256) void k_scanA8(const uint32_t* __restrict__ deg,
                                                uint32_t* __restrict__ partials) {
    __shared__ uint32_t sbuf[256];
    long base = (long)blockIdx.x * 1024 + threadIdx.x * 4;
    uint32_t s = 0;
    if (base + 3 < NP) {
        uint4 v = *(const uint4*)&deg[base];
        s = v.x + v.y + v.z + v.w;
    } else {
        for (int j = 0; j < 4; ++j) if (base + j < NP) s += deg[base + j];
    }
    sbuf[threadIdx.x] = s;
    __syncthreads();
    for (int off = 128; off > 0; off >>= 1) {
        if (threadIdx.x < off) sbuf[threadIdx.x] += sbuf[threadIdx.x + off];
        __syncthreads();
    }
    if (threadIdx.x == 0) partials[blockIdx.x] = sbuf[0];
}

__global__ __launch_bounds__(1024) void k_scanB8(const uint32_t* __restrict__ partials,
                                                 uint32_t* __restrict__ poff,
                                                 uint32_t* __restrict__ starts) {
    __shared__ uint32_t sbuf[1024];
    int t = threadIdx.x;
    uint32_t v = t < SCAN8_NB ? partials[t] : 0u;
    sbuf[t] = v;
    __syncthreads();
    for (int off = 1; off < 1024; off <<= 1) {
        uint32_t add = t >= off ? sbuf[t - off] : 0u;
        __syncthreads();
        sbuf[t] += add;
        __syncthreads();
    }
    if (t < SCAN8_NB) poff[t] = sbuf[t] - v;            // exclusive
    if (t == SCAN8_NB - 1) starts[NP] = sbuf[t];        // sentinel = E
}

__global__ __launch_bounds__(256) void k_scanC8(const uint32_t* __restrict__ deg,
                                                const uint32_t* __restrict__ poff,
                                                uint32_t* __restrict__ starts,
                                                uint32_t* __restrict__ cur) {
    __shared__ uint32_t sbuf[256];
    long base = (long)blockIdx.x * 1024 + threadIdx.x * 4;
    uint32_t v[4] = {0, 0, 0, 0};
    if (base + 3 < NP) {
        uint4 q = *(const uint4*)&deg[base];
        v[0] = q.x; v[1] = q.y; v[2] = q.z; v[3] = q.w;
    } else {
        for (int j = 0; j < 4; ++j) if (base + j < NP) v[j] = deg[base + j];
    }
    uint32_t ts = v[0] + v[1] + v[2] + v[3];
    sbuf[threadIdx.x] = ts;
    __syncthreads();
    for (int off = 1; off < 256; off <<= 1) {
        uint32_t add = threadIdx.x >= off ? sbuf[threadIdx.x - off] : 0u;
        __syncthreads();
        sbuf[threadIdx.x] += add;
        __syncthreads();
    }
    uint32_t run = poff[blockIdx.x] + sbuf[threadIdx.x] - ts;
    for (int j = 0; j < 4; ++j) {
        if (base + j < NP) {
            starts[base + j] = run;
            cur[base + j]    = run;
            run += v[j];
        }
    }
}

// ---------------- per-node total degree + 100K scan -> startsF ----------------
__global__ __launch_bounds__(256) void k_degsum(const uint32_t* __restrict__ deg8,
                                                uint32_t* __restrict__ degF) {
    int n = blockIdx.x * 256 + threadIdx.x;
    if (n < N_NODES) {
        uint32_t s = 0;
#pragma unroll
        for (int p = 0; p < NPART; ++p) s += deg8[(long)p * N_NODES + n];
        degF[n] = s;
    }
}

__global__ __launch_bounds__(256) void k_scanAF(const uint32_t* __restrict__ deg,
                                                uint32_t* __restrict__ partials) {
    __shared__ uint32_t sbuf[256];
    int idx = blockIdx.x * 256 + threadIdx.x;
    uint32_t v = idx < N_NODES ? deg[idx] : 0u;
    sbuf[threadIdx.x] = v;
    __syncthreads();
    for (int off = 128; off > 0; off >>= 1) {
        if (threadIdx.x < off) sbuf[threadIdx.x] += sbuf[threadIdx.x + off];
        __syncthreads();
    }
    if (threadIdx.x == 0) partials[blockIdx.x] = sbuf[0];
}

__global__ __launch_bounds__(512) void k_scanBF(const uint32_t* __restrict__ partials,
                                                uint32_t* __restrict__ poff,
                                                uint32_t* __restrict__ starts) {
    __shared__ uint32_t sbuf[512];
    int t = threadIdx.x;
    uint32_t v = t < SCANF_NB ? partials[t] : 0u;
    sbuf[t] = v;
    __syncthreads();
    for (int off = 1; off < 512; off <<= 1) {
        uint32_t add = t >= off ? sbuf[t - off] : 0u;
        __syncthreads();
        sbuf[t] += add;
        __syncthreads();
    }
    if (t < SCANF_NB) poff[t] = sbuf[t] - v;
    if (t == SCANF_NB - 1) starts[N_NODES] = sbuf[t];
}

__global__ __launch_bounds__(256) void k_scanCF(const uint32_t* __restrict__ deg,
                                                const uint32_t* __restrict__ poff,
                                                uint32_t* __restrict__ starts) {
    __shared__ uint32_t sbuf[256];
    int idx = blockIdx.x * 256 + threadIdx.x;
    uint32_t v = idx < N_NODES ? deg[idx] : 0u;
    sbuf[threadIdx.x] = v;
    __syncthreads();
    for (int off = 1; off < 256; off <<= 1) {
        uint32_t add = threadIdx.x >= off ? sbuf[threadIdx.x - off] : 0u;
        __syncthreads();
        sbuf[threadIdx.x] += add;
        __syncthreads();
    }
    if (idx < N_NODES) starts[idx] = poff[blockIdx.x] + sbuf[threadIdx.x] - v;
}

// ---------------- partitioned reorder (L2-local writes) ----------------
__global__ __launch_bounds__(256) void k_reorder8(const void* __restrict__ ei,
                                                  const float* __restrict__ ew,
                                                  uint32_t* __restrict__ cur8,
                                                  int2* __restrict__ sorted,
                                                  const int* __restrict__ flags) {
    const int mode64 = flags[0];
    const int* p32 = (const int*)ei;
    const long pbase = (long)(blockIdx.x & (NPART - 1)) * N_NODES;
    for (long e = (long)blockIdx.x * 256 + threadIdx.x; e < N_EDGES;
         e += (long)EGRID * 256) {
        int s, d; load_edge(p32, mode64, e, s, d);
        float w = ew[e];
        uint32_t pos = atomicAdd(&cur8[pbase + d], 1u);
        sorted[pos] = make_int2(s, __float_as_int(w));
    }
}

// ---------------- merge: partitioned CSR -> single node-major CSR ----------------
// wave per node: read 8 segments (sequential), write contiguous (coalesced)
__global__ __launch_bounds__(256) void k_merge(const int2* __restrict__ tmp,
                                               const uint32_t* __restrict__ starts8,
                                               const uint32_t* __restrict__ startsF,
                                               int2* __restrict__ dst) {
    const int lane = threadIdx.x & 63;
    const int n = blockIdx.x * 4 + (threadIdx.x >> 6);
    uint32_t sv = 0, lv = 0;
    if (lane < NPART) {
        sv = starts8[(long)lane * N_NODES + n];
        lv = starts8[(long)lane * N_NODES + n + 1] - sv;
    }
    // inclusive prefix of lv over lanes (only 0..7 meaningful)
    uint32_t pv = lv;
#pragma unroll
    for (int off = 1; off < 8; off <<= 1) {
        uint32_t t = __shfl_up(pv, off, 64);
        if (lane >= off) pv += t;
    }
    uint32_t ev_ = pv - lv;  // exclusive prefix on lanes 0..7
    uint32_t tot = __shfl((int)pv, 7, 64);
    uint32_t base = startsF[n];
    uint32_t e1v = __shfl((int)ev_, 1, 64), e2v = __shfl((int)ev_, 2, 64),
             e3v = __shfl((int)ev_, 3, 64), e4v = __shfl((int)ev_, 4, 64),
             e5v = __shfl((int)ev_, 5, 64), e6v = __shfl((int)ev_, 6, 64),
             e7v = __shfl((int)ev_, 7, 64);
    uint32_t s0v = __shfl((int)sv, 0, 64), s1v = __shfl((int)sv, 1, 64),
             s2v = __shfl((int)sv, 2, 64), s3v = __shfl((int)sv, 3, 64),
             s4v = __shfl((int)sv, 4, 64), s5v = __shfl((int)sv, 5, 64),
             s6v = __shfl((int)sv, 6, 64), s7v = __shfl((int)sv, 7, 64);
    for (uint32_t i = lane; i < tot; i += 64) {
        uint32_t eb = 0, sb = s0v;
        if (i >= e1v) { eb = e1v; sb = s1v; }
        if (i >= e2v) { eb = e2v; sb = s2v; }
        if (i >= e3v) { eb = e3v; sb = s3v; }
        if (i >= e4v) { eb = e4v; sb = s4v; }
        if (i >= e5v) { eb = e5v; sb = s5v; }
        if (i >= e6v) { eb = e6v; sb = s6v; }
        if (i >= e7v) { eb = e7v; sb = s7v; }
        dst[base + i] = tmp[sb + (i - eb)];
    }
}

// ---------------- pre-pack W1 into bf16 hi/lo B-fragments ----------------
__global__ __launch_bounds__(256) void k_packW(const float* __restrict__ W1,
                                               ushort* __restrict__ Wpack) {
    const int ks = blockIdx.x;        // 0..11
    const int t  = threadIdx.x;
    const int nt = t >> 6, l = t & 63;
    ushort hs[8], ls[8];
#pragma unroll
    for (int j = 0; j < 8; ++j) {
        float wv = W1[(ks * 32 + (l >> 4) * 8 + j) * 64 + nt * 16 + (l & 15)];
        ushort h = f2bf(wv);
        hs[j] = h;
        ls[j] = f2bf(wv - bf2f(h));
    }
    *(short8_t*)&Wpack[((8 * ks + nt) * 64 + l) * 8]     = *(short8_t*)hs;
    *(short8_t*)&Wpack[((8 * ks + 4 + nt) * 64 + l) * 8] = *(short8_t*)ls;
}

// ---------------- GEMM1: H = bf16((x .* m1 * 2) @ W1), no LDS ----------------
__global__ __launch_bounds__(256) void k1_mfma(
        const float* __restrict__ x, const void* __restrict__ m1,
        const ushort* __restrict__ Wpack, ushort* __restrict__ Hb,
        const int* __restrict__ flags) {
    const int mmode = flags[1];
    const int t = threadIdx.x;
    const int l = t & 63, w = t >> 6;
    const int node0 = blockIdx.x * 64;
    const long row = node0 + w * 16 + (l & 15);
    const int kq = (l >> 4) * 8;
    const bool valid = row < N_NODES;

    f32x4 acc[4];
#pragma unroll
    for (int i = 0; i < 4; ++i) acc[i] = (f32x4)0.0f;

    for (int ks = 0; ks < 12; ++ks) {
        float xv[8];
        if (valid) {
            long gb = row * IN_DIM + ks * 32 + kq;
            float4 x0 = *(const float4*)(x + gb);
            float4 x1 = *(const float4*)(x + gb + 4);
            xv[0] = x0.x; xv[1] = x0.y; xv[2] = x0.z; xv[3] = x0.w;
            xv[4] = x1.x; xv[5] = x1.y; xv[6] = x1.z; xv[7] = x1.w;
            float mv[8];
            if (mmode == 0) {
                const ushort* mp = (const ushort*)m1 + gb;
                ushort4 a = *(const ushort4*)mp;
                ushort4 b = *(const ushort4*)(mp + 4);
                mv[0] = a.x ? 2.f : 0.f; mv[1] = a.y ? 2.f : 0.f;
                mv[2] = a.z ? 2.f : 0.f; mv[3] = a.w ? 2.f : 0.f;
                mv[4] = b.x ? 2.f : 0.f; mv[5] = b.y ? 2.f : 0.f;
                mv[6] = b.z ? 2.f : 0.f; mv[7] = b.w ? 2.f : 0.f;
            } else if (mmode == 2) {
                const float* mp = (const float*)m1 + gb;
                float4 a = *(const float4*)mp;
                float4 b = *(const float4*)(mp + 4);
                mv[0] = a.x != 0.f ? 2.f : 0.f; mv[1] = a.y != 0.f ? 2.f : 0.f;
                mv[2] = a.z != 0.f ? 2.f : 0.f; mv[3] = a.w != 0.f ? 2.f : 0.f;
                mv[4] = b.x != 0.f ? 2.f : 0.f; mv[5] = b.y != 0.f ? 2.f : 0.f;
                mv[6] = b.z != 0.f ? 2.f : 0.f; mv[7] = b.w != 0.f ? 2.f : 0.f;
            } else if (mmode == 3) {
                uint2 mb = *(const uint2*)((const uint8_t*)m1 + gb);
#pragma unroll
                for (int j = 0; j < 4; ++j) {
                    mv[j]     = ((mb.x >> (8 * j)) & 0xffu) ? 2.f : 0.f;
                    mv[4 + j] = ((mb.y >> (8 * j)) & 0xffu) ? 2.f : 0.f;
                }
            } else {
                const int* mp = (const int*)m1 + gb;
                int4 a = *(const int4*)mp;
                int4 b = *(const int4*)(mp + 4);
                mv[0] = a.x ? 2.f : 0.f; mv[1] = a.y ? 2.f : 0.f;
                mv[2] = a.z ? 2.f : 0.f; mv[3] = a.w ? 2.f : 0.f;
                mv[4] = b.x ? 2.f : 0.f; mv[5] = b.y ? 2.f : 0.f;
                mv[6] = b.z ? 2.f : 0.f; mv[7] = b.w ? 2.f : 0.f;
            }
#pragma unroll
            for (int j = 0; j < 8; ++j) xv[j] *= mv[j];
        } else {
#pragma unroll
            for (int j = 0; j < 8; ++j) xv[j] = 0.0f;
        }
        ushort ap[8];
#pragma unroll
        for (int j = 0; j < 8; ++j) ap[j] = f2bf(xv[j]);
        short8_t ah = *(short8_t*)ap;

#pragma unroll
        for (int nt = 0; nt < 4; ++nt) {
            short8_t bh = *(const short8_t*)&Wpack[((8 * ks + nt) * 64 + l) * 8];
            short8_t bl = *(const short8_t*)&Wpack[((8 * ks + 4 + nt) * 64 + l) * 8];
            acc[nt] = __builtin_amdgcn_mfma_f32_16x16x32_bf16(ah, bh, acc[nt], 0, 0, 0);
            acc[nt] = __builtin_amdgcn_mfma_f32_16x16x32_bf16(ah, bl, acc[nt], 0, 0, 0);
        }
    }
    const int r0 = (l >> 4) * 4;
#pragma unroll
    for (int nt = 0; nt < 4; ++nt) {
#pragma unroll
        for (int r = 0; r < 4; ++r) {
            long node = node0 + w * 16 + r0 + r;
            if (node < N_NODES)
                Hb[node * 64 + nt * 16 + (l & 15)] = f2bf(acc[nt][r]);
        }
    }
}

// ---------------- single-CSR gather: batched coalesced edge load + shfl ----------
__device__ __forceinline__ float agg_nodeF(const ushort* __restrict__ Hb,
                                           const int2* __restrict__ sorted,
                                           const uint32_t* __restrict__ starts,
                                           int n, int lane) {
    uint32_t e = starts[n], e1 = starts[n + 1];
    float acc0 = 0.f, acc1 = 0.f, acc2 = 0.f, acc3 = 0.f;
    while (e < e1) {
        uint32_t rem = e1 - e;
        uint32_t cnt = rem < 64u ? rem : 64u;
        uint32_t idx = e + (uint32_t)lane;
        if (idx >= e1) idx = e1 - 1;
        int2 my = sorted[idx];        // one coalesced 512B wave load
        uint32_t j = 0;
        for (; j + 4 <= cnt; j += 4) {
            int sA = __shfl(my.x, (int)j + 0, 64), wA = __shfl(my.y, (int)j + 0, 64);
            int sB = __shfl(my.x, (int)j + 1, 64), wB = __shfl(my.y, (int)j + 1, 64);
            int sC = __shfl(my.x, (int)j + 2, 64), wC = __shfl(my.y, (int)j + 2, 64);
            int sD = __shfl(my.x, (int)j + 3, 64), wD = __shfl(my.y, (int)j + 3, 64);
            float vA = bf2f(Hb[(long)sA * 64 + lane]);
            float vB = bf2f(Hb[(long)sB * 64 + lane]);
            float vC = bf2f(Hb[(long)sC * 64 + lane]);
            float vD = bf2f(Hb[(long)sD * 64 + lane]);
            acc0 = fmaf(vA, __int_as_float(wA), acc0);
            acc1 = fmaf(vB, __int_as_float(wB), acc1);
            acc2 = fmaf(vC, __int_as_float(wC), acc2);
            acc3 = fmaf(vD, __int_as_float(wD), acc3);
        }
        for (; j < cnt; ++j) {
            int sA = __shfl(my.x, (int)j, 64), wA = __shfl(my.y, (int)j, 64);
            acc0 = fmaf(bf2f(Hb[(long)sA * 64 + lane]), __int_as_float(wA), acc0);
        }
        e += cnt;
    }
    return (acc0 + acc1) + (acc2 + acc3);
}

// ---------------- fused: agg1 + b1 + relu + mask2 + @W2 -> bf16 ----------------
// grid must be exactly N_NODES/4 blocks.
__global__ __launch_bounds__(256) void k_aggmlp(
        const ushort* __restrict__ Hb, const int2* __restrict__ sorted,
        const uint32_t* __restrict__ starts, const float* __restrict__ b1,
        const void* __restrict__ m2, const float* __restrict__ W2,
        ushort* __restrict__ H2b, const int* __restrict__ flags) {
    __shared__ float w2s[64 * 64];
    __shared__ float vbuf[4][64];
    const int mmode = flags[1];
    for (int i = threadIdx.x; i < 4096; i += 256) w2s[i] = W2[i];
    __syncthreads();

    const int lane = threadIdx.x & 63;
    const int w = threadIdx.x >> 6;
    const int n = blockIdx.x * 4 + w;
    float acc = agg_nodeF(Hb, sorted, starts, n, lane);
    float u = acc + b1[lane];
    u = u > 0.0f ? u : 0.0f;
    u *= mask_at(m2, mmode, (long)n * 64 + lane);
    vbuf[w][lane] = u;  // wave-local LDS: in-order, no barrier needed
    float h2 = 0.0f;
#pragma unroll
    for (int j = 0; j < 64; j += 4) {
        float4 v4 = *(const float4*)&vbuf[w][j];
        h2 = fmaf(v4.x, w2s[(j + 0) * 64 + lane], h2);
        h2 = fmaf(v4.y, w2s[(j + 1) * 64 + lane], h2);
        h2 = fmaf(v4.z, w2s[(j + 2) * 64 + lane], h2);
        h2 = fmaf(v4.w, w2s[(j + 3) * 64 + lane], h2);
    }
    H2b[(long)n * 64 + lane] = f2bf(h2);
}

// ---------------- final: out = b2 + agg2, f32 out ----------------
__global__ __launch_bounds__(256) void k_agg(const ushort* __restrict__ Hb,
                                             const int2* __restrict__ sorted,
                                             const uint32_t* __restrict__ starts,
                                             const float* __restrict__ bias,
                                             float* __restrict__ dest) {
    const int lane = threadIdx.x & 63;
    const int n = blockIdx.x * 4 + (threadIdx.x >> 6);
    if (n >= N_NODES) return;
    float acc = bias[lane] + agg_nodeF(Hb, sorted, starts, n, lane);
    dest[(long)n * 64 + lane] = acc;
}

// ---------------- fallback atomic path ----------------
__global__ __launch_bounds__(256) void k_scatter(
        const ushort* __restrict__ Hb, const void* __restrict__ ei,
        const float* __restrict__ ew, float* __restrict__ dest,
        const int* __restrict__ flags) {
    const int mode64 = flags[0];
    const int lane = threadIdx.x & 63;
    const long wid = (long)blockIdx.x * 4 + (threadIdx.x >> 6);
    const long nw = (long)gridDim.x * 4;
    const int* p32 = (const int*)ei;
    for (long e = wid; e < N_EDGES; e += nw) {
        int s, d; load_edge(p32, mode64, e, s, d);
        float w = ew[e];
        float v = bf2f(Hb[(long)s * 64 + lane]) * w;
        atomicAdd(&dest[(long)d * 64 + lane], v);
    }
}

__global__ __launch_bounds__(256) void k3_mlp(
        const float* __restrict__ agg, const float* __restrict__ b1,
        const void* __restrict__ m2, const float* __restrict__ W2,
        ushort* __restrict__ H2b, const int* __restrict__ flags) {
    __shared__ float w2s[64 * 64];
    __shared__ float vbuf[4][64];
    const int mmode = flags[1];
    for (int i = threadIdx.x; i < 4096; i += 256) w2s[i] = W2[i];
    __syncthreads();
    const int lane = threadIdx.x & 63;
    const int w = threadIdx.x >> 6;
    const float bc = b1[lane];
    const long wid = (long)blockIdx.x * 4 + w;
    const long nw = (long)gridDim.x * 4;
    for (long n = wid; n < N_NODES; n += nw) {
        float u = agg[n * 64 + lane] + bc;
        u = u > 0.0f ? u : 0.0f;
        u *= mask_at(m2, mmode, n * 64 + lane);
        vbuf[w][lane] = u;
        float acc = 0.0f;
#pragma unroll
        for (int j = 0; j < 64; j += 4) {
            float4 v4 = *(const float4*)&vbuf[w][j];
            acc = fmaf(v4.x, w2s[(j + 0) * 64 + lane], acc);
            acc = fmaf(v4.y, w2s[(j + 1) * 64 + lane], acc);
            acc = fmaf(v4.z, w2s[(j + 2) * 64 + lane], acc);
            acc = fmaf(v4.w, w2s[(j + 3) * 64 + lane], acc);
        }
        H2b[n * 64 + lane] = f2bf(acc);
    }
}

__global__ void k_init_out(float* __restrict__ out, const float* __restrict__ b2) {
    const long total = (long)N_NODES * 16;
    for (long j = (long)blockIdx.x * 256 + threadIdx.x; j < total;
         j += (long)gridDim.x * 256) {
        ((float4*)out)[j] = ((const float4*)b2)[j & 15];
    }
}

extern "C" void kernel_launch(void* const* d_in, const int* in_sizes, int n_in,
                              void* d_out, int out_size, void* d_ws, size_t ws_size,
                              hipStream_t stream) {
    const float* x  = (const float*)d_in[0];
    const void*  ei = d_in[1];
    const float* ew = (const float*)d_in[2];
    const float* W1 = (const float*)d_in[3];
    const float* b1 = (const float*)d_in[4];
    const float* W2 = (const float*)d_in[5];
    const float* b2 = (const float*)d_in[6];
    const void*  m1 = d_in[7];
    const void*  m2 = d_in[8];
    float* out = (float*)d_out;

    char* ws = (char*)d_ws;
    size_t off = 0;
    auto alloc = [&](size_t bytes) {
        char* p = ws + off;
        off += (bytes + 255) & ~(size_t)255;
        return p;
    };
    int*    flags = (int*)alloc(32);
    ushort* Hb    = (ushort*)alloc((size_t)N_NODES * 64 * 2);
    ushort* H2b   = (ushort*)alloc((size_t)N_NODES * 64 * 2);
    int2*   sorted8 = (int2*)alloc((size_t)N_EDGES * 8);   // tmp partitioned CSR
    int2*   sortedF = (int2*)alloc((size_t)N_EDGES * 8);   // final node-major CSR
    float*  AGG   = (float*)sorted8;                       // fallback alias (25.6MB)
    uint32_t* starts8 = (uint32_t*)alloc((size_t)(NP + 64) * 4);
    uint32_t* cur8    = (uint32_t*)alloc((size_t)NP * 4);
    uint32_t* deg8    = (uint32_t*)alloc((size_t)NP * 4);
    uint32_t* degF    = (uint32_t*)alloc((size_t)N_NODES * 4);
    uint32_t* startsF = (uint32_t*)alloc((size_t)(N_NODES + 64) * 4);
    uint32_t* part8   = (uint32_t*)alloc((size_t)SCAN8_NB * 4);
    uint32_t* poff8   = (uint32_t*)alloc((size_t)SCAN8_NB * 4);
    uint32_t* partF   = (uint32_t*)alloc((size_t)SCANF_NB * 4);
    uint32_t* poffF   = (uint32_t*)alloc((size_t)SCANF_NB * 4);
    ushort*   Wpack   = (ushort*)alloc((size_t)12 * 8 * 64 * 8 * 2);
    size_t need = off;

    hipLaunchKernelGGL(k_detect, dim3(1), dim3(64), 0, stream,
                       (const uint32_t*)ei, (const uint32_t*)m1, flags);
    hipLaunchKernelGGL(k_packW, dim3(12), dim3(256), 0, stream, W1, Wpack);

    if (ws_size >= need) {
        // --- partitioned build -> merged single CSR ---
        hipMemsetAsync(deg8, 0, (size_t)NP * 4, stream);
        hipLaunchKernelGGL(k_hist8, dim3(EGRID), dim3(256), 0, stream,
                           ei, deg8, flags);
        hipLaunchKernelGGL(k_scanA8, dim3(SCAN8_NB), dim3(256), 0, stream,
                           deg8, part8);
        hipLaunchKernelGGL(k_scanB8, dim3(1), dim3(1024), 0, stream,
                           part8, poff8, starts8);
        hipLaunchKernelGGL(k_scanC8, dim3(SCAN8_NB), dim3(256), 0, stream,
                           deg8, poff8, starts8, cur8);
        hipLaunchKernelGGL(k_reorder8, dim3(EGRID), dim3(256), 0, stream,
                           ei, ew, cur8, sorted8, flags);
        hipLaunchKernelGGL(k_degsum, dim3(SCANF_NB), dim3(256), 0, stream,
                           deg8, degF);
        hipLaunchKernelGGL(k_scanAF, dim3(SCANF_NB), dim3(256), 0, stream,
                           degF, partF);
        hipLaunchKernelGGL(k_scanBF, dim3(1), dim3(512), 0, stream,
                           partF, poffF, startsF);
        hipLaunchKernelGGL(k_scanCF, dim3(SCANF_NB), dim3(256), 0, stream,
                           degF, poffF, startsF);
        hipLaunchKernelGGL(k_merge, dim3(N_NODES / 4), dim3(256), 0, stream,
                           sorted8, starts8, startsF, sortedF);
        hipLaunchKernelGGL(k1_mfma, dim3((N_NODES + 63) / 64), dim3(256), 0, stream,
                           x, m1, Wpack, Hb, flags);
        hipLaunchKernelGGL(k_aggmlp, dim3(N_NODES / 4), dim3(256), 0, stream,
                           Hb, sortedF, startsF, b1, m2, W2, H2b, flags);
        hipLaunchKernelGGL(k_agg, dim3(N_NODES / 4), dim3(256), 0, stream,
                           H2b, sortedF, startsF, b2, out);
    } else {
        // --- fallback: atomic path ---
        hipMemsetAsync(AGG, 0, (size_t)N_NODES * 64 * 4, stream);
        hipLaunchKernelGGL(k1_mfma, dim3((N_NODES + 63) / 64), dim3(256), 0, stream,
                           x, m1, Wpack, Hb, flags);
        hipLaunchKernelGGL(k_scatter, dim3(4096), dim3(256), 0, stream,
                           Hb, ei, ew, AGG, flags);
        hipLaunchKernelGGL(k3_mlp, dim3(1024), dim3(256), 0, stream,
                           AGG, b1, m2, W2, H2b, flags);
        hipLaunchKernelGGL(k_init_out, dim3(2048), dim3(256), 0, stream, out, b2);
        hipLaunchKernelGGL(k_scatter, dim3(4096), dim3(256), 0, stream,
                           H2b, ei, ew, out, flags);
    }
}